// Round 12
// baseline (573.743 us; speedup 1.0000x reference)
//
#include <hip/hip_runtime.h>
#include <hip/hip_fp16.h>

// Problem constants (from reference)
#define Nn 200000
#define Ee 6400000
#define EP 6600000            // Ee + Nn self loops
#define Hh 9
#define Ll 4
#define Gg 2000
#define Cc 2
#define JK 36                 // Ll * Hh
#define NCB ((Nn + 1023) >> 10) // 196 coarse buckets (1024 nodes each)
#define NGB (Nn / 32)         // 6250 groups of 32 nodes
#define EPB 8192              // edges per phase-A block
#define NBLKA ((EP + EPB - 1) / EPB) // 806
#define NB ((Nn + 255) / 256) // 782
#define NPB 32                // nodes per k_node_agg block (oct per node)
#define NAB (Nn / NPB)        // 6250 blocks
#define CAP2 4096             // kB2 LDS sort capacity (mean 1056, +90 sigma)
#define HTS (NCB + 1)         // histT row stride

union H2F { __half2 h; float f; };

// ========= CSR build: block-major multisplit + two-stage bucket sort =========

// Phase A: per-block LDS multisplit, drained BLOCK-MAJOR (straight coalesced
// copy, no global coordination). Per-block bucket offsets -> histT row;
// global bucket totals -> ctot.
// Payload: src (18b) | dst low 10 bits << 18.
__global__ __launch_bounds__(256) void kA_scatter(
    const int* __restrict__ src, const int* __restrict__ dst,
    int* __restrict__ ctot, int* __restrict__ histT,
    unsigned* __restrict__ bucketed)
{
    __shared__ unsigned pbuf[EPB];        // 32 KB
    __shared__ int lh[NCB];
    __shared__ int s[256];
    int t = threadIdx.x;
    if (t < NCB) lh[t] = 0;
    __syncthreads();
    const int base = blockIdx.x * EPB;
    const int nseg = min(EPB, EP - base);
    // pass 1: histogram (dst only)
    for (int j = t; j < nseg; j += 256) {
        int e = base + j;
        int d = (e < Ee) ? dst[e] : (e - Ee);
        atomicAdd(&lh[d >> 10], 1);
    }
    __syncthreads();
    // exclusive scan of 196 bins
    int v = (t < NCB) ? lh[t] : 0;
    s[t] = v; __syncthreads();
    for (int off = 1; off < 256; off <<= 1) {
        int u = (t >= off) ? s[t - off] : 0;
        __syncthreads();
        s[t] += u;
        __syncthreads();
    }
    int* hrow = histT + (size_t)blockIdx.x * HTS;
    if (t < NCB) {
        int ex = s[t] - v;
        lh[t] = ex;                        // LDS cursor
        hrow[t] = ex;                      // run starts for kB1
        if (v) atomicAdd(&ctot[t], v);
    }
    if (t == 0) hrow[NCB] = nseg;
    __syncthreads();
    // pass 2: scatter into LDS (bucket-ordered within block)
    for (int j = t; j < nseg; j += 256) {
        int e = base + j;
        int sv, d;
        if (e < Ee) { sv = src[e]; d = dst[e]; } else { sv = e - Ee; d = sv; }
        int pos = atomicAdd(&lh[d >> 10], 1);
        pbuf[pos] = (unsigned)sv | ((unsigned)(d & 1023) << 18);
    }
    __syncthreads();
    // pass 3: straight coalesced drain, block-major
    for (int j = t; j < nseg; j += 256)
        bucketed[base + j] = pbuf[j];
}

// Scan coarse totals -> cbase; terminators.
__global__ __launch_bounds__(256) void k_scan(
    const int* __restrict__ ctot, int* __restrict__ cbase,
    int* __restrict__ row_ptr, int* __restrict__ bin_ptr)
{
    __shared__ int s[256];
    int t = threadIdx.x;
    int v = (t < NCB) ? ctot[t] : 0;
    s[t] = v; __syncthreads();
    for (int off = 1; off < 256; off <<= 1) {
        int u = (t >= off) ? s[t - off] : 0;
        __syncthreads();
        s[t] += u;
        __syncthreads();
    }
    if (t < NCB) cbase[t] = s[t] - v;
    if (t == 0) { cbase[NCB] = EP; row_ptr[Nn] = EP; bin_ptr[NGB] = EP; }
}

// Stage B1: one 1024-thread block per coarse bucket, sort to 32 bins of
// 32 nodes. A bin's write window is ~4KB filling from a 1/32 share of the
// read stream -> dense writes, amp ~1. Keeps node-in-group tag (bits 18..22).
__global__ __launch_bounds__(1024) void kB1_sort32(
    const unsigned* __restrict__ bucketed, const int* __restrict__ histT,
    const int* __restrict__ cbase, int* __restrict__ bin_ptr,
    int* __restrict__ csr_mid)
{
    __shared__ int lh[16][32];            // per-wave privatized hist
    __shared__ int cur[32];
    const int k = blockIdx.x;
    const int t = threadIdx.x;
    const int w = t >> 6, lane = t & 63;  // 16 waves
    if (t < 512) ((int*)lh)[t] = 0;
    __syncthreads();
    for (int b = w; b < NBLKA; b += 16) {
        const int* hrow = histT + (size_t)b * HTS;
        int s0 = hrow[k], s1 = hrow[k + 1];
        int rb = b * EPB;
        for (int j = s0 + lane; j < s1; j += 64)
            atomicAdd(&lh[w][(bucketed[rb + j] >> 23) & 31], 1);
    }
    __syncthreads();
    if (t == 0) {
        int run = cbase[k];
        for (int b2 = 0; b2 < 32; ++b2) {
            int c = 0;
#pragma unroll
            for (int w2 = 0; w2 < 16; ++w2) c += lh[w2][b2];
            cur[b2] = run;
            bin_ptr[(k << 5) + b2] = run;
            run += c;
        }
    }
    __syncthreads();
    for (int b = w; b < NBLKA; b += 16) {
        const int* hrow = histT + (size_t)b * HTS;
        int s0 = hrow[k], s1 = hrow[k + 1];
        int rb = b * EPB;
        for (int j = s0 + lane; j < s1; j += 64) {
            unsigned p = bucketed[rb + j];
            int pos = atomicAdd(&cur[(p >> 23) & 31], 1);
            csr_mid[pos] = (int)(p & 0x7FFFFFu);   // src + node5 tag
        }
    }
}

// Stage B2: one block per 32-node group (contiguous after B1). Full sort by
// node inside LDS, coalesced write-back IN PLACE; row_ptr analytic.
// Fallback (statistically unreachable) scatters via the dead bucketed array.
__global__ __launch_bounds__(256) void kB2_sortnode(
    int* __restrict__ csr_mid, const int* __restrict__ bin_ptr,
    int* __restrict__ row_ptr, unsigned* __restrict__ scratch)
{
    __shared__ unsigned ebuf[CAP2];
    __shared__ unsigned obuf[CAP2];
    __shared__ int h32[32];
    __shared__ int cur[32];
    const int g = blockIdx.x;
    const int t = threadIdx.x;
    const int beg = bin_ptr[g], end = bin_ptr[g + 1];
    const int n = end - beg;
    if (t < 32) h32[t] = 0;
    __syncthreads();
    if (n <= CAP2) {
        for (int j = t; j < n; j += 256) {
            unsigned p = (unsigned)csr_mid[beg + j];
            ebuf[j] = p;
            atomicAdd(&h32[(p >> 18) & 31], 1);
        }
        __syncthreads();
        if (t == 0) {
            int run = 0;
            for (int b = 0; b < 32; ++b) {
                cur[b] = run;
                row_ptr[(g << 5) + b] = beg + run;
                run += h32[b];
            }
        }
        __syncthreads();
        for (int j = t; j < n; j += 256) {
            unsigned p = ebuf[j];
            int pos = atomicAdd(&cur[(p >> 18) & 31], 1);
            obuf[pos] = p & 0x3FFFFu;             // strip tag
        }
        __syncthreads();
        for (int j = t; j < n; j += 256)
            csr_mid[beg + j] = (int)obuf[j];
    } else {
        // fallback: global two-pass via scratch (bucketed region, dead here)
        for (int j = t; j < n; j += 256)
            atomicAdd(&h32[((unsigned)csr_mid[beg + j] >> 18) & 31], 1);
        __syncthreads();
        if (t == 0) {
            int run = 0;
            for (int b = 0; b < 32; ++b) {
                cur[b] = run;
                row_ptr[(g << 5) + b] = beg + run;
                run += h32[b];
            }
        }
        __syncthreads();
        for (int j = t; j < n; j += 256) {
            unsigned p = (unsigned)csr_mid[beg + j];
            int pos = atomicAdd(&cur[(p >> 18) & 31], 1);
            scratch[beg + pos] = p & 0x3FFFFu;
        }
        __syncthreads();
        for (int j = t; j < n; j += 256)
            csr_mid[beg + j] = (int)scratch[beg + j];
    }
}

// ============ per-layer kernels ============

// h line layout per node: 32 B = 8 floats.
//   floats[0..3] = h0..h7 as 4x half2, float[4] low half = h8,
//   float[5] = alpha_s (fp32), float[6] = alpha_d (fp32), float[7] pad.
__global__ __launch_bounds__(256) void k_transform(
    const float* __restrict__ xin, int xstride,
    const float* __restrict__ Wl,
    const float* __restrict__ asrc, const float* __restrict__ adst,
    float* __restrict__ h)
{
    int i = blockIdx.x * blockDim.x + threadIdx.x;
    if (i >= Nn) return;
    const float* xp = xin + (size_t)i * xstride;
    float xi[Hh];
#pragma unroll
    for (int k = 0; k < Hh; ++k) xi[k] = xp[k];
    float hv[Hh];
#pragma unroll
    for (int j = 0; j < Hh; ++j) {
        float s = 0.f;
#pragma unroll
        for (int k = 0; k < Hh; ++k) s += xi[k] * Wl[k * Hh + j];
        hv[j] = s;
    }
    float as = 0.f, ad = 0.f;
#pragma unroll
    for (int j = 0; j < Hh; ++j) { as += hv[j] * asrc[j]; ad += hv[j] * adst[j]; }
    H2F u01, u23, u45, u67, u8p;
    u01.h = __floats2half2_rn(hv[0], hv[1]);
    u23.h = __floats2half2_rn(hv[2], hv[3]);
    u45.h = __floats2half2_rn(hv[4], hv[5]);
    u67.h = __floats2half2_rn(hv[6], hv[7]);
    u8p.h = __floats2half2_rn(hv[8], 0.f);
    float4* hp = (float4*)(h + ((size_t)i << 3));
    hp[0] = make_float4(u01.f, u23.f, u45.f, u67.f);
    hp[1] = make_float4(u8p.f, as, ad, 0.f);
}

// Oct-per-node gather, DIRECT csr reads (no LDS staging): consecutive nodes'
// segments are adjacent, so a wave's 8 octs read near-contiguous csr — same
// coalescing as the staging pass, minus the pass, barrier, and 12KB LDS.
// Single-pass softmax: |logits| << 88 so exp never overflows; ratio exact.
__global__ __launch_bounds__(256) void k_node_agg(
    const int* __restrict__ rp, const int* __restrict__ csr,
    const float* __restrict__ h, const float* __restrict__ biasl,
    float* __restrict__ jk, int l)
{
    __shared__ int srp[NPB + 1];
    const int nbase = blockIdx.x * NPB;
    const int t = threadIdx.x;
    if (t <= NPB) srp[t] = rp[nbase + t];   // nbase+NPB <= Nn; rp[Nn] = EP
    __syncthreads();

    const int ni = t >> 3;          // node within block
    const int q  = t & 7;           // lane within oct
    const int i  = nbase + ni;
    const float c = h[((size_t)i << 3) + 6];   // own alpha_d (fp32)
    const int beg = srp[ni], end = srp[ni + 1];
    float a0=0,a1=0,a2=0,a3=0,a4=0,a5=0,a6=0,a7=0,a8=0,den=0;
    int idx = beg + q;
    int s = (idx < end) ? csr[idx] : 0;
    while (idx < end) {
        int nidx = idx + 8;
        int sn = (nidx < end) ? csr[nidx] : 0;     // prefetch next src
        const float4* hp = (const float4*)(h + ((size_t)s << 3));
        float4 F0 = hp[0], F1 = hp[1];
        float lg = F1.y + c;
        lg = lg > 0.f ? lg : 0.2f * lg;            // leaky_relu(0.2)
        float w = __expf(lg);
        H2F u; float2 p;
        u.f = F0.x; p = __half22float2(u.h); a0 += w*p.x; a1 += w*p.y;
        u.f = F0.y; p = __half22float2(u.h); a2 += w*p.x; a3 += w*p.y;
        u.f = F0.z; p = __half22float2(u.h); a4 += w*p.x; a5 += w*p.y;
        u.f = F0.w; p = __half22float2(u.h); a6 += w*p.x; a7 += w*p.y;
        u.f = F1.x; p = __half22float2(u.h); a8 += w*p.x;
        den += w;
        idx = nidx; s = sn;
    }
#pragma unroll
    for (int m = 1; m <= 4; m <<= 1) {
        a0 += __shfl_xor(a0, m); a1 += __shfl_xor(a1, m);
        a2 += __shfl_xor(a2, m); a3 += __shfl_xor(a3, m);
        a4 += __shfl_xor(a4, m); a5 += __shfl_xor(a5, m);
        a6 += __shfl_xor(a6, m); a7 += __shfl_xor(a7, m);
        a8 += __shfl_xor(a8, m); den += __shfl_xor(den, m);
    }
    if (q == 0) {
        float inv = 1.f / den;          // den >= 1 (self-loop term)
        float* jp = jk + (size_t)i * JK + l * Hh;
        float o;
        o = a0*inv + biasl[0]; jp[0] = fmaxf(o, 0.f);
        o = a1*inv + biasl[1]; jp[1] = fmaxf(o, 0.f);
        o = a2*inv + biasl[2]; jp[2] = fmaxf(o, 0.f);
        o = a3*inv + biasl[3]; jp[3] = fmaxf(o, 0.f);
        o = a4*inv + biasl[4]; jp[4] = fmaxf(o, 0.f);
        o = a5*inv + biasl[5]; jp[5] = fmaxf(o, 0.f);
        o = a6*inv + biasl[6]; jp[6] = fmaxf(o, 0.f);
        o = a7*inv + biasl[7]; jp[7] = fmaxf(o, 0.f);
        o = a8*inv + biasl[8]; jp[8] = fmaxf(o, 0.f);
    }
}

// ============ pool + fc ============

// One block per graph: t -> (row-lane, col). Row reads are contiguous 144B
// -> fully coalesced; LDS reduce over 7 row-lanes. Post-relu values >= 0;
// m=0 init reproduces the isfinite->0 guard for empty graphs.
__device__ __forceinline__ int lower_bound_batch(const int* b, int v) {
    int lo = 0, hi = Nn;
    while (lo < hi) { int m = (lo + hi) >> 1; if (b[m] < v) lo = m + 1; else hi = m; }
    return lo;
}

__global__ __launch_bounds__(256) void k_pool_seg(
    const float* __restrict__ jk, const int* __restrict__ batch,
    float* __restrict__ pooled)
{
    __shared__ int sbe[2];
    __shared__ float red[7][JK];
    const int g = blockIdx.x;
    const int t = threadIdx.x;
    if (t < 2) sbe[t] = lower_bound_batch(batch, g + t);
    __syncthreads();
    const int beg = sbe[0], end = sbe[1];
    if (t < 252) {
        const int col = t % JK, rl = t / JK;      // rl in [0,7)
        float m = 0.f;
        for (int r = beg + rl; r < end; r += 7)
            m = fmaxf(m, jk[(size_t)r * JK + col]);
        red[rl][col] = m;
    }
    __syncthreads();
    if (t < JK) {
        float m = red[0][t];
#pragma unroll
        for (int rl = 1; rl < 7; ++rl) m = fmaxf(m, red[rl][t]);
        pooled[(size_t)g * JK + t] = m;
    }
}

__global__ __launch_bounds__(256) void k_fc(
    const float* __restrict__ pooled, const float* __restrict__ fcw,
    const float* __restrict__ fcb, float* __restrict__ out)
{
    int t = blockIdx.x * blockDim.x + threadIdx.x;
    if (t >= Gg * Cc) return;
    int g = t / Cc, c = t - g * Cc;
    float s = fcb[c];
    const float* pp = pooled + (size_t)g * JK;
#pragma unroll
    for (int j = 0; j < JK; ++j) s += pp[j] * fcw[j * Cc + c];
    out[t] = s;
}

extern "C" void kernel_launch(void* const* d_in, const int* in_sizes, int n_in,
                              void* d_out, int out_size, void* d_ws, size_t ws_size,
                              hipStream_t stream) {
    const float* x      = (const float*)d_in[0];   // [N,9]
    const int*   ei     = (const int*)d_in[1];     // [2,E]: src row then dst row
    const int*   batch  = (const int*)d_in[2];     // [N] sorted
    const float* W      = (const float*)d_in[3];   // [L,9,9]
    const float* a_src  = (const float*)d_in[4];   // [L,9]
    const float* a_dst  = (const float*)d_in[5];   // [L,9]
    const float* bias   = (const float*)d_in[6];   // [L,9]
    const float* fc_w   = (const float*)d_in[7];   // [36,2]
    const float* fc_b   = (const float*)d_in[8];   // [2]
    float* out = (float*)d_out;

    // Workspace layout (~63 MB live). histT aliases h, bucketed aliases jk —
    // both dead before h/jk are first written (same-stream ordering).
    float* ws        = (float*)d_ws;
    float* h         = ws;                                // Nn*8 floats (6.4MB)
    float* jk        = h + (size_t)Nn * 8;                // Nn*JK (28.8MB)
    float* pooled    = jk + (size_t)Nn * JK;              // Gg*JK
    int* row_ptr     = (int*)(pooled + (size_t)Gg * JK);  // Nn+1
    int* ctot        = row_ptr + Nn + 1;                  // NCB
    int* cbase       = ctot + NCB;                        // NCB+1
    int* bin_ptr     = cbase + NCB + 1;                   // NGB+1
    int* csr_src     = bin_ptr + NGB + 1;                 // EP (26.4MB)
    int* histT       = (int*)h;                           // NBLKA*HTS (0.64MB)
    unsigned* bucketed = (unsigned*)jk;                   // EP alias (26.4MB)

    const int* srcp = ei;
    const int* dstp = ei + Ee;

    // CSR build (edge structure is layer-invariant)
    hipMemsetAsync(ctot, 0, NCB * sizeof(int), stream);
    kA_scatter  <<<NBLKA, 256, 0, stream>>>(srcp, dstp, ctot, histT, bucketed);
    k_scan      <<<1, 256, 0, stream>>>(ctot, cbase, row_ptr, bin_ptr);
    kB1_sort32  <<<NCB, 1024, 0, stream>>>(bucketed, histT, cbase, bin_ptr, csr_src);
    kB2_sortnode<<<NGB, 256, 0, stream>>>(csr_src, bin_ptr, row_ptr, bucketed);

    for (int l = 0; l < Ll; ++l) {
        const float* xin = (l == 0) ? x : (jk + (size_t)(l - 1) * Hh);
        int xstride      = (l == 0) ? Hh : JK;
        k_transform<<<NB, 256, 0, stream>>>(xin, xstride, W + l * Hh * Hh,
                                            a_src + l * Hh, a_dst + l * Hh, h);
        k_node_agg<<<NAB, 256, 0, stream>>>(row_ptr, csr_src,
                                            h, bias + l * Hh, jk, l);
    }
    k_pool_seg<<<Gg, 256, 0, stream>>>(jk, batch, pooled);
    k_fc<<<(Gg * Cc + 255) / 256, 256, 0, stream>>>(pooled, fc_w, fc_b, out);
}

// Round 13
// 573.274 us; speedup vs baseline: 1.0008x; 1.0008x over previous
//
#include <hip/hip_runtime.h>
#include <hip/hip_fp16.h>

// Problem constants (from reference)
#define Nn 200000
#define Ee 6400000
#define EP 6600000            // Ee + Nn self loops
#define Hh 9
#define Ll 4
#define Gg 2000
#define Cc 2
#define JK 36                 // Ll * Hh
#define NCB ((Nn + 1023) >> 10) // 196 coarse buckets (1024 nodes each)
#define EPB 8192              // edges per phase-A block
#define NBLKA ((EP + EPB - 1) / EPB) // 806
#define NB ((Nn + 255) / 256) // 782
#define NPB 32                // nodes per k_node_agg block (oct per node)
#define NAB (Nn / NPB)        // 6250 blocks
#define CAP 3072              // staged csr entries per k_node_agg block (12 KB)
#define HTS (NCB + 1)         // histT row stride

union H2F { __half2 h; float f; };

// ========= CSR build: block-major multisplit + per-bucket LDS sort =========
// (R9 structure — empirically fastest: kB is atomic-bound, its write amp
//  doesn't cost wall time; two-stage variants were slower.)

// Phase A: per-block LDS multisplit, drained BLOCK-MAJOR (straight coalesced
// copy, no global coordination). Per-block bucket offsets -> histT row;
// global bucket totals -> ctot.
// Payload: src (18b) | dst low 10 bits << 18.
__global__ __launch_bounds__(256) void kA_scatter(
    const int* __restrict__ src, const int* __restrict__ dst,
    int* __restrict__ ctot, int* __restrict__ histT,
    unsigned* __restrict__ bucketed)
{
    __shared__ unsigned pbuf[EPB];        // 32 KB
    __shared__ int lh[NCB];
    __shared__ int s[256];
    int t = threadIdx.x;
    if (t < NCB) lh[t] = 0;
    __syncthreads();
    const int base = blockIdx.x * EPB;
    const int nseg = min(EPB, EP - base);
    // pass 1: histogram (dst only)
    for (int j = t; j < nseg; j += 256) {
        int e = base + j;
        int d = (e < Ee) ? dst[e] : (e - Ee);
        atomicAdd(&lh[d >> 10], 1);
    }
    __syncthreads();
    // exclusive scan of 196 bins
    int v = (t < NCB) ? lh[t] : 0;
    s[t] = v; __syncthreads();
    for (int off = 1; off < 256; off <<= 1) {
        int u = (t >= off) ? s[t - off] : 0;
        __syncthreads();
        s[t] += u;
        __syncthreads();
    }
    int* hrow = histT + (size_t)blockIdx.x * HTS;
    if (t < NCB) {
        int ex = s[t] - v;
        lh[t] = ex;                        // LDS cursor
        hrow[t] = ex;                      // run starts for kB
        if (v) atomicAdd(&ctot[t], v);
    }
    if (t == 0) hrow[NCB] = nseg;
    __syncthreads();
    // pass 2: scatter into LDS (bucket-ordered within block)
    for (int j = t; j < nseg; j += 256) {
        int e = base + j;
        int sv, d;
        if (e < Ee) { sv = src[e]; d = dst[e]; } else { sv = e - Ee; d = sv; }
        int pos = atomicAdd(&lh[d >> 10], 1);
        pbuf[pos] = (unsigned)sv | ((unsigned)(d & 1023) << 18);
    }
    __syncthreads();
    // pass 3: straight coalesced drain, block-major
    for (int j = t; j < nseg; j += 256)
        bucketed[base + j] = pbuf[j];
}

// Scan coarse totals -> cbase.
__global__ __launch_bounds__(256) void k_scan(
    const int* __restrict__ ctot, int* __restrict__ cbase,
    int* __restrict__ row_ptr)
{
    __shared__ int s[256];
    int t = threadIdx.x;
    int v = (t < NCB) ? ctot[t] : 0;
    s[t] = v; __syncthreads();
    for (int off = 1; off < 256; off <<= 1) {
        int u = (t >= off) ? s[t - off] : 0;
        __syncthreads();
        s[t] += u;
        __syncthreads();
    }
    if (t < NCB) cbase[t] = s[t] - v;
    if (t == 0) { cbase[NCB] = EP; row_ptr[Nn] = EP; }
}

// Phase B: ONE 1024-thread block per coarse bucket. Entries live in 806
// short runs (block-major, bounds from histT). 1024-bin LDS counting sort;
// row_ptr analytic.
__global__ __launch_bounds__(1024) void kB_csr(
    const unsigned* __restrict__ bucketed, const int* __restrict__ histT,
    const int* __restrict__ cbase, int* __restrict__ row_ptr,
    int* __restrict__ csr_src)
{
    __shared__ int bh[1024];
    __shared__ int cur[1024];
    const int k = blockIdx.x;
    const int t = threadIdx.x;
    const int w = t >> 6, lane = t & 63;  // 16 waves
    bh[t] = 0;
    __syncthreads();
    for (int b = w; b < NBLKA; b += 16) {
        const int* hrow = histT + (size_t)b * HTS;
        int s0 = hrow[k], s1 = hrow[k + 1];   // same addr all lanes: broadcast
        int rb = b * EPB;
        for (int j = s0 + lane; j < s1; j += 64)
            atomicAdd(&bh[(bucketed[rb + j] >> 18) & 1023], 1);
    }
    __syncthreads();
    int v = bh[t];
    for (int off = 1; off < 1024; off <<= 1) {
        int u = (t >= off) ? bh[t - off] : 0;
        __syncthreads();
        bh[t] += u;
        __syncthreads();
    }
    int pos0 = cbase[k] + bh[t] - v;      // exclusive scan
    int node = (k << 10) + t;
    if (node < Nn) row_ptr[node] = pos0;
    cur[t] = pos0;
    __syncthreads();
    for (int b = w; b < NBLKA; b += 16) {
        const int* hrow = histT + (size_t)b * HTS;
        int s0 = hrow[k], s1 = hrow[k + 1];
        int rb = b * EPB;
        for (int j = s0 + lane; j < s1; j += 64) {
            unsigned p = bucketed[rb + j];
            int pos = atomicAdd(&cur[(p >> 18) & 1023], 1);
            csr_src[pos] = (int)(p & 0x3FFFFu);
        }
    }
}

// ============ per-layer kernels ============

// h line layout per node: 32 B = 8 floats.
//   floats[0..3] = h0..h7 as 4x half2, float[4] low half = h8,
//   float[5] = alpha_s (fp32), float[6] = alpha_d (fp32), float[7] pad.
__global__ __launch_bounds__(256) void k_transform(
    const float* __restrict__ xin, int xstride,
    const float* __restrict__ Wl,
    const float* __restrict__ asrc, const float* __restrict__ adst,
    float* __restrict__ h)
{
    int i = blockIdx.x * blockDim.x + threadIdx.x;
    if (i >= Nn) return;
    const float* xp = xin + (size_t)i * xstride;
    float xi[Hh];
#pragma unroll
    for (int k = 0; k < Hh; ++k) xi[k] = xp[k];
    float hv[Hh];
#pragma unroll
    for (int j = 0; j < Hh; ++j) {
        float s = 0.f;
#pragma unroll
        for (int k = 0; k < Hh; ++k) s += xi[k] * Wl[k * Hh + j];
        hv[j] = s;
    }
    float as = 0.f, ad = 0.f;
#pragma unroll
    for (int j = 0; j < Hh; ++j) { as += hv[j] * asrc[j]; ad += hv[j] * adst[j]; }
    H2F u01, u23, u45, u67, u8p;
    u01.h = __floats2half2_rn(hv[0], hv[1]);
    u23.h = __floats2half2_rn(hv[2], hv[3]);
    u45.h = __floats2half2_rn(hv[4], hv[5]);
    u67.h = __floats2half2_rn(hv[6], hv[7]);
    u8p.h = __floats2half2_rn(hv[8], 0.f);
    float4* hp = (float4*)(h + ((size_t)i << 3));
    hp[0] = make_float4(u01.f, u23.f, u45.f, u67.f);
    hp[1] = make_float4(u8p.f, as, ad, 0.f);
}

// Oct-per-node gather with LDS-staged CSR + 2-edge ILP unroll: each lane
// issues TWO independent 32B h-line loads per iteration (latency-bound on
// L2/L3 gather -> double memory-level parallelism).
// Single-pass softmax: |logits| << 88 so exp never overflows; ratio exact.
__global__ __launch_bounds__(256) void k_node_agg(
    const int* __restrict__ rp, const int* __restrict__ csr,
    const float* __restrict__ h, const float* __restrict__ biasl,
    float* __restrict__ jk, int l)
{
    __shared__ int scsr[CAP];
    __shared__ int srp[NPB + 1];
    const int nbase = blockIdx.x * NPB;
    const int t = threadIdx.x;
    if (t <= NPB) srp[t] = rp[nbase + t];   // nbase+NPB <= Nn; rp[Nn] = EP
    __syncthreads();
    const int beg_blk = srp[0];
    const int nseg = srp[NPB] - beg_blk;
    const bool use_lds = (nseg <= CAP);
    if (use_lds)
        for (int j = t; j < nseg; j += 256) scsr[j] = csr[beg_blk + j];
    __syncthreads();

    const int ni = t >> 3;          // node within block
    const int q  = t & 7;           // lane within oct
    const int i  = nbase + ni;
    const float c = h[((size_t)i << 3) + 6];   // own alpha_d (fp32)
    const int beg = srp[ni], end = srp[ni + 1];
    float a0=0,a1=0,a2=0,a3=0,a4=0,a5=0,a6=0,a7=0,a8=0,den=0;
    if (use_lds) {
        int idx = beg - beg_blk + q;
        const int iend = end - beg_blk;
        // 2-edge unrolled body: two independent h-line loads in flight
        while (idx + 8 < iend) {
            int s0 = scsr[idx];
            int s1 = scsr[idx + 8];
            const float4* hpa = (const float4*)(h + ((size_t)s0 << 3));
            const float4* hpb = (const float4*)(h + ((size_t)s1 << 3));
            float4 A0 = hpa[0], A1 = hpa[1];
            float4 B0 = hpb[0], B1 = hpb[1];
            float lga = A1.y + c; lga = lga > 0.f ? lga : 0.2f * lga;
            float lgb = B1.y + c; lgb = lgb > 0.f ? lgb : 0.2f * lgb;
            float wa = __expf(lga), wb = __expf(lgb);
            H2F u; float2 p;
            u.f = A0.x; p = __half22float2(u.h); a0 += wa*p.x; a1 += wa*p.y;
            u.f = A0.y; p = __half22float2(u.h); a2 += wa*p.x; a3 += wa*p.y;
            u.f = A0.z; p = __half22float2(u.h); a4 += wa*p.x; a5 += wa*p.y;
            u.f = A0.w; p = __half22float2(u.h); a6 += wa*p.x; a7 += wa*p.y;
            u.f = A1.x; p = __half22float2(u.h); a8 += wa*p.x;
            u.f = B0.x; p = __half22float2(u.h); a0 += wb*p.x; a1 += wb*p.y;
            u.f = B0.y; p = __half22float2(u.h); a2 += wb*p.x; a3 += wb*p.y;
            u.f = B0.z; p = __half22float2(u.h); a4 += wb*p.x; a5 += wb*p.y;
            u.f = B0.w; p = __half22float2(u.h); a6 += wb*p.x; a7 += wb*p.y;
            u.f = B1.x; p = __half22float2(u.h); a8 += wb*p.x;
            den += wa + wb;
            idx += 16;
        }
        if (idx < iend) {
            int s0 = scsr[idx];
            const float4* hpa = (const float4*)(h + ((size_t)s0 << 3));
            float4 A0 = hpa[0], A1 = hpa[1];
            float lg = A1.y + c; lg = lg > 0.f ? lg : 0.2f * lg;
            float w = __expf(lg);
            H2F u; float2 p;
            u.f = A0.x; p = __half22float2(u.h); a0 += w*p.x; a1 += w*p.y;
            u.f = A0.y; p = __half22float2(u.h); a2 += w*p.x; a3 += w*p.y;
            u.f = A0.z; p = __half22float2(u.h); a4 += w*p.x; a5 += w*p.y;
            u.f = A0.w; p = __half22float2(u.h); a6 += w*p.x; a7 += w*p.y;
            u.f = A1.x; p = __half22float2(u.h); a8 += w*p.x;
            den += w;
        }
    } else {
        for (int e = beg + q; e < end; e += 8) {
            int s = csr[e];
            const float4* hp = (const float4*)(h + ((size_t)s << 3));
            float4 F0 = hp[0], F1 = hp[1];
            float lg = F1.y + c;
            lg = lg > 0.f ? lg : 0.2f * lg;
            float w = __expf(lg);
            H2F u; float2 p;
            u.f = F0.x; p = __half22float2(u.h); a0 += w*p.x; a1 += w*p.y;
            u.f = F0.y; p = __half22float2(u.h); a2 += w*p.x; a3 += w*p.y;
            u.f = F0.z; p = __half22float2(u.h); a4 += w*p.x; a5 += w*p.y;
            u.f = F0.w; p = __half22float2(u.h); a6 += w*p.x; a7 += w*p.y;
            u.f = F1.x; p = __half22float2(u.h); a8 += w*p.x;
            den += w;
        }
    }
#pragma unroll
    for (int m = 1; m <= 4; m <<= 1) {
        a0 += __shfl_xor(a0, m); a1 += __shfl_xor(a1, m);
        a2 += __shfl_xor(a2, m); a3 += __shfl_xor(a3, m);
        a4 += __shfl_xor(a4, m); a5 += __shfl_xor(a5, m);
        a6 += __shfl_xor(a6, m); a7 += __shfl_xor(a7, m);
        a8 += __shfl_xor(a8, m); den += __shfl_xor(den, m);
    }
    if (q == 0) {
        float inv = 1.f / den;          // den >= 1 (self-loop term)
        float* jp = jk + (size_t)i * JK + l * Hh;
        float o;
        o = a0*inv + biasl[0]; jp[0] = fmaxf(o, 0.f);
        o = a1*inv + biasl[1]; jp[1] = fmaxf(o, 0.f);
        o = a2*inv + biasl[2]; jp[2] = fmaxf(o, 0.f);
        o = a3*inv + biasl[3]; jp[3] = fmaxf(o, 0.f);
        o = a4*inv + biasl[4]; jp[4] = fmaxf(o, 0.f);
        o = a5*inv + biasl[5]; jp[5] = fmaxf(o, 0.f);
        o = a6*inv + biasl[6]; jp[6] = fmaxf(o, 0.f);
        o = a7*inv + biasl[7]; jp[7] = fmaxf(o, 0.f);
        o = a8*inv + biasl[8]; jp[8] = fmaxf(o, 0.f);
    }
}

// ============ pool + fc ============

// Fused segmented max: batch is sorted, graph range via binary search.
// Post-relu values >= 0; init 0 reproduces the isfinite->0 guard.
__device__ __forceinline__ int lower_bound_batch(const int* b, int v) {
    int lo = 0, hi = Nn;
    while (lo < hi) { int m = (lo + hi) >> 1; if (b[m] < v) lo = m + 1; else hi = m; }
    return lo;
}

__global__ __launch_bounds__(256) void k_pool_seg(
    const float* __restrict__ jk, const int* __restrict__ batch,
    float* __restrict__ pooled)
{
    int t = blockIdx.x * 256 + threadIdx.x;
    if (t >= Gg * JK) return;
    int g = t / JK, col = t - g * JK;
    int beg = lower_bound_batch(batch, g);
    int end = lower_bound_batch(batch, g + 1);
    float m = 0.f;
    for (int i = beg; i < end; ++i)
        m = fmaxf(m, jk[(size_t)i * JK + col]);
    pooled[t] = m;
}

__global__ __launch_bounds__(256) void k_fc(
    const float* __restrict__ pooled, const float* __restrict__ fcw,
    const float* __restrict__ fcb, float* __restrict__ out)
{
    int t = blockIdx.x * blockDim.x + threadIdx.x;
    if (t >= Gg * Cc) return;
    int g = t / Cc, c = t - g * Cc;
    float s = fcb[c];
    const float* pp = pooled + (size_t)g * JK;
#pragma unroll
    for (int j = 0; j < JK; ++j) s += pp[j] * fcw[j * Cc + c];
    out[t] = s;
}

extern "C" void kernel_launch(void* const* d_in, const int* in_sizes, int n_in,
                              void* d_out, int out_size, void* d_ws, size_t ws_size,
                              hipStream_t stream) {
    const float* x      = (const float*)d_in[0];   // [N,9]
    const int*   ei     = (const int*)d_in[1];     // [2,E]: src row then dst row
    const int*   batch  = (const int*)d_in[2];     // [N] sorted
    const float* W      = (const float*)d_in[3];   // [L,9,9]
    const float* a_src  = (const float*)d_in[4];   // [L,9]
    const float* a_dst  = (const float*)d_in[5];   // [L,9]
    const float* bias   = (const float*)d_in[6];   // [L,9]
    const float* fc_w   = (const float*)d_in[7];   // [36,2]
    const float* fc_b   = (const float*)d_in[8];   // [2]
    float* out = (float*)d_out;

    // Workspace layout (~63 MB live). histT aliases h, bucketed aliases jk —
    // both dead before h/jk are first written (same-stream ordering).
    float* ws        = (float*)d_ws;
    float* h         = ws;                                // Nn*8 floats (6.4MB)
    float* jk        = h + (size_t)Nn * 8;                // Nn*JK (28.8MB)
    float* pooled    = jk + (size_t)Nn * JK;              // Gg*JK
    int* row_ptr     = (int*)(pooled + (size_t)Gg * JK);  // Nn+1
    int* ctot        = row_ptr + Nn + 1;                  // NCB
    int* cbase       = ctot + NCB;                        // NCB+1
    int* csr_src     = cbase + NCB + 1;                   // EP (26.4MB)
    int* histT       = (int*)h;                           // NBLKA*HTS (0.64MB)
    unsigned* bucketed = (unsigned*)jk;                   // EP alias (26.4MB)

    const int* srcp = ei;
    const int* dstp = ei + Ee;

    // CSR build (edge structure is layer-invariant)
    hipMemsetAsync(ctot, 0, NCB * sizeof(int), stream);
    kA_scatter<<<NBLKA, 256, 0, stream>>>(srcp, dstp, ctot, histT, bucketed);
    k_scan    <<<1, 256, 0, stream>>>(ctot, cbase, row_ptr);
    kB_csr    <<<NCB, 1024, 0, stream>>>(bucketed, histT, cbase, row_ptr, csr_src);

    for (int l = 0; l < Ll; ++l) {
        const float* xin = (l == 0) ? x : (jk + (size_t)(l - 1) * Hh);
        int xstride      = (l == 0) ? Hh : JK;
        k_transform<<<NB, 256, 0, stream>>>(xin, xstride, W + l * Hh * Hh,
                                            a_src + l * Hh, a_dst + l * Hh, h);
        k_node_agg<<<NAB, 256, 0, stream>>>(row_ptr, csr_src,
                                            h, bias + l * Hh, jk, l);
    }
    k_pool_seg<<<(Gg * JK + 255) / 256, 256, 0, stream>>>(jk, batch, pooled);
    k_fc<<<(Gg * Cc + 255) / 256, 256, 0, stream>>>(pooled, fc_w, fc_b, out);
}

// Round 14
// 542.244 us; speedup vs baseline: 1.0581x; 1.0572x over previous
//
#include <hip/hip_runtime.h>
#include <hip/hip_fp16.h>

// Problem constants (from reference)
#define Nn 200000
#define Ee 6400000
#define EP 6600000            // Ee + Nn self loops
#define Hh 9
#define Ll 4
#define Gg 2000
#define Cc 2
#define JK 36                 // Ll * Hh
#define NCB ((Nn + 1023) >> 10) // 196 coarse buckets (1024 nodes each)
#define EPB 8192              // edges per phase-A block
#define NBLKA ((EP + EPB - 1) / EPB) // 806
#define NB ((Nn + 255) / 256) // 782
#define NPB 32                // nodes per k_node_agg block (oct per node)
#define NAB (Nn / NPB)        // 6250 blocks
#define CAP 3072              // staged csr entries per block (12 KB)
#define HTS (NCB + 1)         // histT row stride

union H2F { __half2 h; float f; };

// ========= CSR build: block-major multisplit + per-bucket LDS sort =========
// (R9 configuration — empirically fastest across R9..R13.)

// Phase A: per-block LDS multisplit, drained BLOCK-MAJOR (straight coalesced
// copy, no global coordination). Per-block bucket offsets -> histT row;
// global bucket totals -> ctot.
// Payload: src (18b) | dst low 10 bits << 18.
__global__ __launch_bounds__(256) void kA_scatter(
    const int* __restrict__ src, const int* __restrict__ dst,
    int* __restrict__ ctot, int* __restrict__ histT,
    unsigned* __restrict__ bucketed)
{
    __shared__ unsigned pbuf[EPB];        // 32 KB
    __shared__ int lh[NCB];
    __shared__ int s[256];
    int t = threadIdx.x;
    if (t < NCB) lh[t] = 0;
    __syncthreads();
    const int base = blockIdx.x * EPB;
    const int nseg = min(EPB, EP - base);
    // pass 1: histogram (dst only)
    for (int j = t; j < nseg; j += 256) {
        int e = base + j;
        int d = (e < Ee) ? dst[e] : (e - Ee);
        atomicAdd(&lh[d >> 10], 1);
    }
    __syncthreads();
    // exclusive scan of 196 bins
    int v = (t < NCB) ? lh[t] : 0;
    s[t] = v; __syncthreads();
    for (int off = 1; off < 256; off <<= 1) {
        int u = (t >= off) ? s[t - off] : 0;
        __syncthreads();
        s[t] += u;
        __syncthreads();
    }
    int* hrow = histT + (size_t)blockIdx.x * HTS;
    if (t < NCB) {
        int ex = s[t] - v;
        lh[t] = ex;                        // LDS cursor
        hrow[t] = ex;                      // run starts for kB
        if (v) atomicAdd(&ctot[t], v);
    }
    if (t == 0) hrow[NCB] = nseg;
    __syncthreads();
    // pass 2: scatter into LDS (bucket-ordered within block)
    for (int j = t; j < nseg; j += 256) {
        int e = base + j;
        int sv, d;
        if (e < Ee) { sv = src[e]; d = dst[e]; } else { sv = e - Ee; d = sv; }
        int pos = atomicAdd(&lh[d >> 10], 1);
        pbuf[pos] = (unsigned)sv | ((unsigned)(d & 1023) << 18);
    }
    __syncthreads();
    // pass 3: straight coalesced drain, block-major
    for (int j = t; j < nseg; j += 256)
        bucketed[base + j] = pbuf[j];
}

// Scan coarse totals -> cbase.
__global__ __launch_bounds__(256) void k_scan(
    const int* __restrict__ ctot, int* __restrict__ cbase,
    int* __restrict__ row_ptr)
{
    __shared__ int s[256];
    int t = threadIdx.x;
    int v = (t < NCB) ? ctot[t] : 0;
    s[t] = v; __syncthreads();
    for (int off = 1; off < 256; off <<= 1) {
        int u = (t >= off) ? s[t - off] : 0;
        __syncthreads();
        s[t] += u;
        __syncthreads();
    }
    if (t < NCB) cbase[t] = s[t] - v;
    if (t == 0) { cbase[NCB] = EP; row_ptr[Nn] = EP; }
}

// Phase B: ONE 1024-thread block per coarse bucket. Entries live in 806
// short runs (block-major, bounds from histT). 1024-bin LDS counting sort;
// row_ptr analytic. Atomic-latency-bound; write amp here is cosmetic
// (two-stage low-amp variants measured slower in wall time).
__global__ __launch_bounds__(1024) void kB_csr(
    const unsigned* __restrict__ bucketed, const int* __restrict__ histT,
    const int* __restrict__ cbase, int* __restrict__ row_ptr,
    int* __restrict__ csr_src)
{
    __shared__ int bh[1024];
    __shared__ int cur[1024];
    const int k = blockIdx.x;
    const int t = threadIdx.x;
    const int w = t >> 6, lane = t & 63;  // 16 waves
    bh[t] = 0;
    __syncthreads();
    for (int b = w; b < NBLKA; b += 16) {
        const int* hrow = histT + (size_t)b * HTS;
        int s0 = hrow[k], s1 = hrow[k + 1];   // same addr all lanes: broadcast
        int rb = b * EPB;
        for (int j = s0 + lane; j < s1; j += 64)
            atomicAdd(&bh[(bucketed[rb + j] >> 18) & 1023], 1);
    }
    __syncthreads();
    int v = bh[t];
    for (int off = 1; off < 1024; off <<= 1) {
        int u = (t >= off) ? bh[t - off] : 0;
        __syncthreads();
        bh[t] += u;
        __syncthreads();
    }
    int pos0 = cbase[k] + bh[t] - v;      // exclusive scan
    int node = (k << 10) + t;
    if (node < Nn) row_ptr[node] = pos0;
    cur[t] = pos0;
    __syncthreads();
    for (int b = w; b < NBLKA; b += 16) {
        const int* hrow = histT + (size_t)b * HTS;
        int s0 = hrow[k], s1 = hrow[k + 1];
        int rb = b * EPB;
        for (int j = s0 + lane; j < s1; j += 64) {
            unsigned p = bucketed[rb + j];
            int pos = atomicAdd(&cur[(p >> 18) & 1023], 1);
            csr_src[pos] = (int)(p & 0x3FFFFu);
        }
    }
}

// ============ per-layer kernels ============

// h line layout per node: 32 B = 8 floats.
//   floats[0..3] = h0..h7 as 4x half2, float[4] low half = h8,
//   float[5] = alpha_s (fp32), float[6] = alpha_d (fp32), float[7] pad.
__global__ __launch_bounds__(256) void k_transform(
    const float* __restrict__ xin, int xstride,
    const float* __restrict__ Wl,
    const float* __restrict__ asrc, const float* __restrict__ adst,
    float* __restrict__ h)
{
    int i = blockIdx.x * blockDim.x + threadIdx.x;
    if (i >= Nn) return;
    const float* xp = xin + (size_t)i * xstride;
    float xi[Hh];
#pragma unroll
    for (int k = 0; k < Hh; ++k) xi[k] = xp[k];
    float hv[Hh];
#pragma unroll
    for (int j = 0; j < Hh; ++j) {
        float s = 0.f;
#pragma unroll
        for (int k = 0; k < Hh; ++k) s += xi[k] * Wl[k * Hh + j];
        hv[j] = s;
    }
    float as = 0.f, ad = 0.f;
#pragma unroll
    for (int j = 0; j < Hh; ++j) { as += hv[j] * asrc[j]; ad += hv[j] * adst[j]; }
    H2F u01, u23, u45, u67, u8p;
    u01.h = __floats2half2_rn(hv[0], hv[1]);
    u23.h = __floats2half2_rn(hv[2], hv[3]);
    u45.h = __floats2half2_rn(hv[4], hv[5]);
    u67.h = __floats2half2_rn(hv[6], hv[7]);
    u8p.h = __floats2half2_rn(hv[8], 0.f);
    float4* hp = (float4*)(h + ((size_t)i << 3));
    hp[0] = make_float4(u01.f, u23.f, u45.f, u67.f);
    hp[1] = make_float4(u8p.f, as, ad, 0.f);
}

// Oct-per-node gather with LDS-staged CSR + single-step prefetch (measured
// best across staged/direct/2-unroll variants — R9/R11 form).
// Single-pass softmax: |logits| << 88 so exp never overflows; ratio exact.
__global__ __launch_bounds__(256) void k_node_agg(
    const int* __restrict__ rp, const int* __restrict__ csr,
    const float* __restrict__ h, const float* __restrict__ biasl,
    float* __restrict__ jk, int l)
{
    __shared__ int scsr[CAP];
    __shared__ int srp[NPB + 1];
    const int nbase = blockIdx.x * NPB;
    const int t = threadIdx.x;
    if (t <= NPB) srp[t] = rp[nbase + t];   // nbase+NPB <= Nn; rp[Nn] = EP
    __syncthreads();
    const int beg_blk = srp[0];
    const int nseg = srp[NPB] - beg_blk;
    const bool use_lds = (nseg <= CAP);
    if (use_lds)
        for (int j = t; j < nseg; j += 256) scsr[j] = csr[beg_blk + j];
    __syncthreads();

    const int ni = t >> 3;          // node within block
    const int q  = t & 7;           // lane within oct
    const int i  = nbase + ni;
    const float c = h[((size_t)i << 3) + 6];   // own alpha_d (fp32)
    float a0=0,a1=0,a2=0,a3=0,a4=0,a5=0,a6=0,a7=0,a8=0,den=0;
    if (use_lds) {
        int idx = srp[ni] - beg_blk + q;
        const int iend = srp[ni + 1] - beg_blk;
        int s = (idx < iend) ? scsr[idx] : 0;
        while (idx < iend) {
            int nidx = idx + 8;
            int sn = (nidx < iend) ? scsr[nidx] : 0;   // prefetch next src
            const float4* hp = (const float4*)(h + ((size_t)s << 3));
            float4 F0 = hp[0], F1 = hp[1];
            float lg = F1.y + c;
            lg = lg > 0.f ? lg : 0.2f * lg;            // leaky_relu(0.2)
            float w = __expf(lg);
            H2F u; float2 p;
            u.f = F0.x; p = __half22float2(u.h); a0 += w*p.x; a1 += w*p.y;
            u.f = F0.y; p = __half22float2(u.h); a2 += w*p.x; a3 += w*p.y;
            u.f = F0.z; p = __half22float2(u.h); a4 += w*p.x; a5 += w*p.y;
            u.f = F0.w; p = __half22float2(u.h); a6 += w*p.x; a7 += w*p.y;
            u.f = F1.x; p = __half22float2(u.h); a8 += w*p.x;
            den += w;
            idx = nidx; s = sn;
        }
    } else {
        for (int e = srp[ni] + q; e < srp[ni + 1]; e += 8) {
            int s = csr[e];
            const float4* hp = (const float4*)(h + ((size_t)s << 3));
            float4 F0 = hp[0], F1 = hp[1];
            float lg = F1.y + c;
            lg = lg > 0.f ? lg : 0.2f * lg;
            float w = __expf(lg);
            H2F u; float2 p;
            u.f = F0.x; p = __half22float2(u.h); a0 += w*p.x; a1 += w*p.y;
            u.f = F0.y; p = __half22float2(u.h); a2 += w*p.x; a3 += w*p.y;
            u.f = F0.z; p = __half22float2(u.h); a4 += w*p.x; a5 += w*p.y;
            u.f = F0.w; p = __half22float2(u.h); a6 += w*p.x; a7 += w*p.y;
            u.f = F1.x; p = __half22float2(u.h); a8 += w*p.x;
            den += w;
        }
    }
#pragma unroll
    for (int m = 1; m <= 4; m <<= 1) {
        a0 += __shfl_xor(a0, m); a1 += __shfl_xor(a1, m);
        a2 += __shfl_xor(a2, m); a3 += __shfl_xor(a3, m);
        a4 += __shfl_xor(a4, m); a5 += __shfl_xor(a5, m);
        a6 += __shfl_xor(a6, m); a7 += __shfl_xor(a7, m);
        a8 += __shfl_xor(a8, m); den += __shfl_xor(den, m);
    }
    if (q == 0) {
        float inv = 1.f / den;          // den >= 1 (self-loop term)
        float* jp = jk + (size_t)i * JK + l * Hh;
        float o;
        o = a0*inv + biasl[0]; jp[0] = fmaxf(o, 0.f);
        o = a1*inv + biasl[1]; jp[1] = fmaxf(o, 0.f);
        o = a2*inv + biasl[2]; jp[2] = fmaxf(o, 0.f);
        o = a3*inv + biasl[3]; jp[3] = fmaxf(o, 0.f);
        o = a4*inv + biasl[4]; jp[4] = fmaxf(o, 0.f);
        o = a5*inv + biasl[5]; jp[5] = fmaxf(o, 0.f);
        o = a6*inv + biasl[6]; jp[6] = fmaxf(o, 0.f);
        o = a7*inv + biasl[7]; jp[7] = fmaxf(o, 0.f);
        o = a8*inv + biasl[8]; jp[8] = fmaxf(o, 0.f);
    }
}

// ============ pool + fc ============

// batch is sorted -> graphs are contiguous node ranges. Build range starts.
__global__ __launch_bounds__(256) void k_graph_ptr(
    const int* __restrict__ batch, int* __restrict__ gp)
{
    int i = blockIdx.x * 256 + threadIdx.x;
    if (i >= Nn) return;
    int b = batch[i];
    if (i == 0) {
        for (int g = 0; g <= b; ++g) gp[g] = 0;
    } else {
        int pb = batch[i - 1];
        for (int g = pb + 1; g <= b; ++g) gp[g] = i;
    }
    if (i == Nn - 1) {
        for (int g = b + 1; g <= Gg; ++g) gp[g] = Nn;
    }
}

// Segmented max, one thread per (graph, col). Post-relu values >= 0 and
// init 0 reproduces the isfinite->0 guard for empty graphs.
__global__ __launch_bounds__(256) void k_pool_seg(
    const float* __restrict__ jk, const int* __restrict__ gp,
    float* __restrict__ pooled)
{
    int t = blockIdx.x * 256 + threadIdx.x;
    if (t >= Gg * JK) return;
    int g = t / JK, col = t - g * JK;
    int beg = gp[g], end = gp[g + 1];
    float m = 0.f;
    for (int i = beg; i < end; ++i)
        m = fmaxf(m, jk[(size_t)i * JK + col]);
    pooled[t] = m;
}

__global__ __launch_bounds__(256) void k_fc(
    const float* __restrict__ pooled, const float* __restrict__ fcw,
    const float* __restrict__ fcb, float* __restrict__ out)
{
    int t = blockIdx.x * blockDim.x + threadIdx.x;
    if (t >= Gg * Cc) return;
    int g = t / Cc, c = t - g * Cc;
    float s = fcb[c];
    const float* pp = pooled + (size_t)g * JK;
#pragma unroll
    for (int j = 0; j < JK; ++j) s += pp[j] * fcw[j * Cc + c];
    out[t] = s;
}

extern "C" void kernel_launch(void* const* d_in, const int* in_sizes, int n_in,
                              void* d_out, int out_size, void* d_ws, size_t ws_size,
                              hipStream_t stream) {
    const float* x      = (const float*)d_in[0];   // [N,9]
    const int*   ei     = (const int*)d_in[1];     // [2,E]: src row then dst row
    const int*   batch  = (const int*)d_in[2];     // [N] sorted
    const float* W      = (const float*)d_in[3];   // [L,9,9]
    const float* a_src  = (const float*)d_in[4];   // [L,9]
    const float* a_dst  = (const float*)d_in[5];   // [L,9]
    const float* bias   = (const float*)d_in[6];   // [L,9]
    const float* fc_w   = (const float*)d_in[7];   // [36,2]
    const float* fc_b   = (const float*)d_in[8];   // [2]
    float* out = (float*)d_out;

    // Workspace layout (~63 MB live). histT aliases h, bucketed aliases jk —
    // both dead before h/jk are first written (same-stream ordering).
    float* ws        = (float*)d_ws;
    float* h         = ws;                                // Nn*8 floats (6.4MB)
    float* jk        = h + (size_t)Nn * 8;                // Nn*JK (28.8MB)
    float* pooled    = jk + (size_t)Nn * JK;              // Gg*JK
    int* row_ptr     = (int*)(pooled + (size_t)Gg * JK);  // Nn+1
    int* gp          = row_ptr + Nn + 1;                  // Gg+1
    int* ctot        = gp + Gg + 1;                       // NCB
    int* cbase       = ctot + NCB;                        // NCB+1
    int* csr_src     = cbase + NCB + 1;                   // EP (26.4MB)
    int* histT       = (int*)h;                           // NBLKA*HTS (0.64MB)
    unsigned* bucketed = (unsigned*)jk;                   // EP alias (26.4MB)

    const int* srcp = ei;
    const int* dstp = ei + Ee;

    // CSR build (edge structure is layer-invariant)
    hipMemsetAsync(ctot, 0, NCB * sizeof(int), stream);
    kA_scatter<<<NBLKA, 256, 0, stream>>>(srcp, dstp, ctot, histT, bucketed);
    k_scan    <<<1, 256, 0, stream>>>(ctot, cbase, row_ptr);
    kB_csr    <<<NCB, 1024, 0, stream>>>(bucketed, histT, cbase, row_ptr, csr_src);

    for (int l = 0; l < Ll; ++l) {
        const float* xin = (l == 0) ? x : (jk + (size_t)(l - 1) * Hh);
        int xstride      = (l == 0) ? Hh : JK;
        k_transform<<<NB, 256, 0, stream>>>(xin, xstride, W + l * Hh * Hh,
                                            a_src + l * Hh, a_dst + l * Hh, h);
        k_node_agg<<<NAB, 256, 0, stream>>>(row_ptr, csr_src,
                                            h, bias + l * Hh, jk, l);
    }
    k_graph_ptr<<<NB, 256, 0, stream>>>(batch, gp);
    k_pool_seg<<<(Gg * JK + 255) / 256, 256, 0, stream>>>(jk, gp, pooled);
    k_fc<<<(Gg * Cc + 255) / 256, 256, 0, stream>>>(pooled, fc_w, fc_b, out);
}